// Round 8
// baseline (2987.925 us; speedup 1.0000x reference)
//
#include <hip/hip_runtime.h>
#include <hip/hip_bf16.h>
#include <math.h>

#define B_   128
#define T_   2048
#define DIN  64
#define H_   128
#define WH_  256
#define WY_  256
#define DOUT 64

typedef __attribute__((ext_vector_type(8))) short short8;
typedef __attribute__((ext_vector_type(4))) float floatx4;

// Raw barrier: wait LDS ops only (global stores stay in flight).
__device__ __forceinline__ void bar_lds() {
    asm volatile("s_waitcnt lgkmcnt(0)\n\ts_barrier" ::: "memory");
}

__device__ __forceinline__ short bf16_hi(float f) {
    __hip_bfloat16 h = __float2bfloat16(f);
    return *reinterpret_cast<short*>(&h);
}
__device__ __forceinline__ float bf16_val(short s) {
    __hip_bfloat16 h = *reinterpret_cast<__hip_bfloat16*>(&s);
    return __bfloat162float(h);
}

// Butterfly sums. permlane16/32 verified (r6: absmax identical to shfl).
__device__ __forceinline__ float red_xor32(float v) {
    float d = v, s = v;
    asm volatile("v_permlane32_swap_b32 %0, %1" : "+v"(d), "+v"(s));
    return d + s;
}
__device__ __forceinline__ float red_xor16(float v) {
    float d = v, s = v;
    asm volatile("v_permlane16_swap_b32 %0, %1" : "+v"(d), "+v"(s));
    return d + s;
}
// xor-8 via DPP row_ror:8 (rotate by 8 within each 16-lane row == lane^8).
// Pure VALU, no DS op.
__device__ __forceinline__ float red_xor8(float v) {
    const int s = __builtin_amdgcn_update_dpp(
        0, __float_as_int(v), 0x128 /*row_ror:8*/, 0xF, 0xF, true);
    return v + __int_as_float(s);
}

// ---------------- Phase 1: sequential recurrence, fp32 VALU ----------------
// 128 WGs (1 batch row) x 512 threads (r6-verified skeleton: 2 barriers/step).
// LDS-inst-minimized mapping: 8 K-groups (kq=lane>>3) x 64 f-octets
// (fo = wave*8 + (lane&7)).
//   GEMV1: thread = 4 outputs (fb1=fo*4) x 24 K-elems; 6 b128 reads
//   GEMV2: thread = 2 outputs (fb2=fo*2) x 32 K-elems; 8 b128 reads
// K-interleave k = kq*4 + jj*32 + e  -> bank = 4*kq: conflict-free.
// Reduce: dpp-ror8 + permlane16 + permlane32 (all VALU).
__global__ __launch_bounds__(512, 2) void rnn_phase1(
    const float* __restrict__ x,
    const float* __restrict__ hW1, const float* __restrict__ hb1,
    const float* __restrict__ hW2, const float* __restrict__ hb2,
    __hip_bfloat16* __restrict__ HallB,  // [T_*B_, H_] bf16
    float* __restrict__ outF)            // d_out; hfinal tail fp32
{
    const int b    = blockIdx.x;
    const int tid  = threadIdx.x;
    const int wave = tid >> 6, lane = tid & 63;

    __shared__ float hx[192];        // [0..127]=h fp32, [128..191]=x_t
    __shared__ float sl[256];

    const int kq  = lane >> 3;               // 0..7
    const int fo  = wave * 8 + (lane & 7);   // 0..63
    const int fb1 = fo * 4;                  // GEMV1 outputs fb1..fb1+3
    const int fb2 = fo * 2;                  // GEMV2 outputs fb2..fb2+1

    // Weights, k-interleaved (compile-time register indices)
    float W1r[4][24];
#pragma unroll
    for (int f = 0; f < 4; ++f)
#pragma unroll
        for (int jj = 0; jj < 6; ++jj)
            *(float4*)&W1r[f][jj * 4] =
                *(const float4*)&hW1[(fb1 + f) * 192 + kq * 4 + jj * 32];
    float W2r[2][32];
#pragma unroll
    for (int f = 0; f < 2; ++f)
#pragma unroll
        for (int jj = 0; jj < 8; ++jj)
            *(float4*)&W2r[f][jj * 4] =
                *(const float4*)&hW2[(fb2 + f) * 256 + kq * 4 + jj * 32];

    const float4 b1v = *(const float4*)&hb1[fb1];
    const float2 b2v = *(const float2*)&hb2[fb2];

    if (tid < 128) hx[tid] = 0.f;
    float xreg = 0.f;
    if (tid >= 448) {
        const int l = tid - 448;
        const long xb = (long)b * (T_ * DIN);
        hx[128 + l] = x[xb + l];        // x_0
        xreg        = x[xb + DIN + l];  // x_1
    }
    __syncthreads();

    for (int t = 0; t < T_; ++t) {
        // ---- Phase A: GEMV1 (4 outputs x 24 K) + VALU reduce + silu -> sl
        {
            float a0 = 0.f, a1 = 0.f, a2 = 0.f, a3 = 0.f;
            const float* hp = &hx[kq * 4];
#pragma unroll
            for (int jj = 0; jj < 6; ++jj) {
                const float4 h4 = *(const float4*)(hp + jj * 32);
                a0 += h4.x * W1r[0][jj*4+0] + h4.y * W1r[0][jj*4+1]
                    + h4.z * W1r[0][jj*4+2] + h4.w * W1r[0][jj*4+3];
                a1 += h4.x * W1r[1][jj*4+0] + h4.y * W1r[1][jj*4+1]
                    + h4.z * W1r[1][jj*4+2] + h4.w * W1r[1][jj*4+3];
                a2 += h4.x * W1r[2][jj*4+0] + h4.y * W1r[2][jj*4+1]
                    + h4.z * W1r[2][jj*4+2] + h4.w * W1r[2][jj*4+3];
                a3 += h4.x * W1r[3][jj*4+0] + h4.y * W1r[3][jj*4+1]
                    + h4.z * W1r[3][jj*4+2] + h4.w * W1r[3][jj*4+3];
            }
            float v0 = red_xor32(red_xor16(red_xor8(a0))) + b1v.x;
            float v1 = red_xor32(red_xor16(red_xor8(a1))) + b1v.y;
            float v2 = red_xor32(red_xor16(red_xor8(a2))) + b1v.z;
            float v3 = red_xor32(red_xor16(red_xor8(a3))) + b1v.w;
            const float s0 = v0 / (1.f + expf(-v0));
            const float s1 = v1 / (1.f + expf(-v1));
            const float s2 = v2 / (1.f + expf(-v2));
            const float s3 = v3 / (1.f + expf(-v3));
            if (lane < 8) *(float4*)&sl[fb1] = make_float4(s0, s1, s2, s3);
        }
        bar_lds();

        // ---- Phase B: GEMV2 (2 outputs x 32 K) + reduce -> h_new; x install
        {
            float c0 = 0.f, c1 = 0.f;
            const float* sp = &sl[kq * 4];
#pragma unroll
            for (int jj = 0; jj < 8; ++jj) {
                const float4 s4 = *(const float4*)(sp + jj * 32);
                c0 += s4.x * W2r[0][jj*4+0] + s4.y * W2r[0][jj*4+1]
                    + s4.z * W2r[0][jj*4+2] + s4.w * W2r[0][jj*4+3];
                c1 += s4.x * W2r[1][jj*4+0] + s4.y * W2r[1][jj*4+1]
                    + s4.z * W2r[1][jj*4+2] + s4.w * W2r[1][jj*4+3];
            }
            const float h0 = red_xor32(red_xor16(red_xor8(c0))) + b2v.x;
            const float h1 = red_xor32(red_xor16(red_xor8(c1))) + b2v.y;
            if (lane < 8) {
                *(float2*)&hx[fb2] = make_float2(h0, h1);
                const unsigned pk =
                    (unsigned)(unsigned short)bf16_hi(h0) |
                    ((unsigned)(unsigned short)bf16_hi(h1) << 16);
                ((unsigned*)HallB)[((long)t * B_ + b) * (H_ / 2) + fo] = pk;
            }
            if (tid >= 448) {                 // x_{t+1} install + prefetch
                const int l = tid - 448;
                hx[128 + l] = xreg;
                const int tn = (t + 2 < T_) ? (t + 2) : (T_ - 1);
                xreg = x[(long)b * (T_ * DIN) + (long)tn * DIN + l];
            }
        }
        bar_lds();
    }

    if (tid < 128)
        outF[(long)B_ * T_ * DOUT + (long)b * H_ + tid] = hx[tid];
}

// -------- pre-split y-weights into MFMA-frag-linear bf16 hi/lo -------------
__global__ __launch_bounds__(256) void presplit(
    const float* __restrict__ yW1, const float* __restrict__ yW2,
    short* __restrict__ Y1f, short* __restrict__ Y2f)
{
    const int i = blockIdx.x * 256 + threadIdx.x;
    if (i < 32768) {
        const int j = i & 7, lane = (i >> 3) & 63, ks = (i >> 9) & 3, nt = i >> 11;
        const float v = yW1[(nt * 16 + (lane & 15)) * 128 + (lane >> 4) * 8 + ks * 32 + j];
        const short h = bf16_hi(v);
        Y1f[i]         = h;
        Y1f[32768 + i] = bf16_hi(v - bf16_val(h));
    }
    if (i < 16384) {
        const int j = i & 7, lane = (i >> 3) & 63, ks = (i >> 9) & 7, nt2 = i >> 12;
        const float v = yW2[(nt2 * 16 + (lane & 15)) * 256 + (lane >> 4) * 8 + ks * 32 + j];
        const short h = bf16_hi(v);
        Y2f[i]         = h;
        Y2f[16384 + i] = bf16_hi(v - bf16_val(h));
    }
}

// ---------------- Phase 2: y-MLP via MFMA, hi/lo split ---------------------
// 2048 WGs x 4 waves; each wave one PAIR of 16-row tiles (32 rows).
__global__ __launch_bounds__(256) void rnn_phase2(
    const __hip_bfloat16* __restrict__ HallB,
    const float* __restrict__ yb1, const float* __restrict__ yb2,
    const short* __restrict__ Y1f, const short* __restrict__ Y2f,
    float* __restrict__ out)
{
    __shared__ short u_lds[4][2][16 * 256];   // per-wave 2 tiles x 8KB

    const int tid  = threadIdx.x;
    const int wave = tid >> 6, lane = tid & 63;
    const int l15  = lane & 15, lg = lane >> 4;
    const long pair = (long)blockIdx.x * 4 + wave;   // 0..8191
    const long r0   = pair * 32;
    const floatx4 zero4 = {0.f, 0.f, 0.f, 0.f};
    const short* Hs = (const short*)HallB;

    short8 aH[2][4];
#pragma unroll
    for (int p = 0; p < 2; ++p)
#pragma unroll
        for (int ks = 0; ks < 4; ++ks)
            aH[p][ks] = *(const short8*)(Hs + (r0 + p * 16 + l15) * 128 + lg * 8 + ks * 32);

    // ---- GEMM1 + silu -> u (bf16) in LDS, XOR-swizzled
#pragma unroll
    for (int nt = 0; nt < 16; ++nt) {
        floatx4 accA = zero4, accB = zero4;
#pragma unroll
        for (int ks = 0; ks < 4; ++ks) {
            const short8 bhi = *(const short8*)(Y1f + ((nt * 4 + ks) * 512 + lane * 8));
            const short8 blo = *(const short8*)(Y1f + 32768 + ((nt * 4 + ks) * 512 + lane * 8));
            accA = __builtin_amdgcn_mfma_f32_16x16x32_bf16(aH[0][ks], bhi, accA, 0, 0, 0);
            accA = __builtin_amdgcn_mfma_f32_16x16x32_bf16(aH[0][ks], blo, accA, 0, 0, 0);
            accB = __builtin_amdgcn_mfma_f32_16x16x32_bf16(aH[1][ks], bhi, accB, 0, 0, 0);
            accB = __builtin_amdgcn_mfma_f32_16x16x32_bf16(aH[1][ks], blo, accB, 0, 0, 0);
        }
        const int col  = nt * 16 + l15;
        const float bias = yb1[col];
#pragma unroll
        for (int r = 0; r < 4; ++r) {
            const int row = lg * 4 + r;
            int byte = row * 512 + col * 2;
            byte ^= ((row & 7) << 4);
            float v = accA[r] + bias;
            *(short*)((char*)u_lds[wave][0] + byte) = bf16_hi(v / (1.f + __expf(-v)));
            v = accB[r] + bias;
            *(short*)((char*)u_lds[wave][1] + byte) = bf16_hi(v / (1.f + __expf(-v)));
        }
    }
    asm volatile("s_waitcnt lgkmcnt(0)" ::: "memory");

    // ---- GEMM2
    floatx4 acc2A[4] = {zero4, zero4, zero4, zero4};
    floatx4 acc2B[4] = {zero4, zero4, zero4, zero4};
#pragma unroll
    for (int ks = 0; ks < 8; ++ks) {
        int byte = l15 * 512 + (lg * 8 + ks * 32) * 2;
        byte ^= ((l15 & 7) << 4);
        const short8 aUa = *(const short8*)((char*)u_lds[wave][0] + byte);
        const short8 aUb = *(const short8*)((char*)u_lds[wave][1] + byte);
#pragma unroll
        for (int nt = 0; nt < 4; ++nt) {
            const short8 bhi = *(const short8*)(Y2f + ((nt * 8 + ks) * 512 + lane * 8));
            const short8 blo = *(const short8*)(Y2f + 16384 + ((nt * 8 + ks) * 512 + lane * 8));
            acc2A[nt] = __builtin_amdgcn_mfma_f32_16x16x32_bf16(aUa, bhi, acc2A[nt], 0, 0, 0);
            acc2A[nt] = __builtin_amdgcn_mfma_f32_16x16x32_bf16(aUa, blo, acc2A[nt], 0, 0, 0);
            acc2B[nt] = __builtin_amdgcn_mfma_f32_16x16x32_bf16(aUb, bhi, acc2B[nt], 0, 0, 0);
            acc2B[nt] = __builtin_amdgcn_mfma_f32_16x16x32_bf16(aUb, blo, acc2B[nt], 0, 0, 0);
        }
    }

    // ---- epilogue: bias + fp32 store (D: col=l15+16nt, row=lg*4+r)
#pragma unroll
    for (int nt = 0; nt < 4; ++nt) {
        const int col  = nt * 16 + l15;
        const float bias = yb2[col];
#pragma unroll
        for (int r = 0; r < 4; ++r) {
            {
                const long R  = r0 + lg * 4 + r;
                const long bb = R & (B_ - 1);
                const long tt = R >> 7;
                out[bb * (T_ * DOUT) + tt * DOUT + col] = acc2A[nt][r] + bias;
            }
            {
                const long R  = r0 + 16 + lg * 4 + r;
                const long bb = R & (B_ - 1);
                const long tt = R >> 7;
                out[bb * (T_ * DOUT) + tt * DOUT + col] = acc2B[nt][r] + bias;
            }
        }
    }
}

extern "C" void kernel_launch(void* const* d_in, const int* in_sizes, int n_in,
                              void* d_out, int out_size, void* d_ws, size_t ws_size,
                              hipStream_t stream) {
    const float* x   = (const float*)d_in[0];
    const float* hW1 = (const float*)d_in[1];
    const float* hb1 = (const float*)d_in[2];
    const float* hW2 = (const float*)d_in[3];
    const float* hb2 = (const float*)d_in[4];
    const float* yW1 = (const float*)d_in[5];
    const float* yb1 = (const float*)d_in[6];
    const float* yW2 = (const float*)d_in[7];
    const float* yb2 = (const float*)d_in[8];

    float* out = (float*)d_out;
    __hip_bfloat16* HallB = (__hip_bfloat16*)d_ws;               // 64 MiB
    const size_t hallBytes = (size_t)T_ * B_ * H_ * sizeof(__hip_bfloat16);
    short* Y1f = (short*)((char*)d_ws + hallBytes);              // 128 KB (hi+lo)
    short* Y2f = Y1f + 65536;                                    // 64 KB

    rnn_phase1<<<128, 512, 0, stream>>>(x, hW1, hb1, hW2, hb2, HallB, out);
    presplit<<<128, 256, 0, stream>>>(yW1, yW2, Y1f, Y2f);
    rnn_phase2<<<2048, 256, 0, stream>>>(HallB, yb1, yb2, Y1f, Y2f, out);
}

// Round 9
// 2485.580 us; speedup vs baseline: 1.2021x; 1.2021x over previous
//
#include <hip/hip_runtime.h>
#include <hip/hip_bf16.h>
#include <math.h>

#define B_   128
#define T_   2048
#define DIN  64
#define H_   128
#define WH_  256
#define WY_  256
#define DOUT 64

typedef __attribute__((ext_vector_type(8))) short short8;
typedef __attribute__((ext_vector_type(4))) float floatx4;

// Raw barrier: wait LDS ops only (global stores stay in flight).
__device__ __forceinline__ void bar_lds() {
    asm volatile("s_waitcnt lgkmcnt(0)\n\ts_barrier" ::: "memory");
}

__device__ __forceinline__ short bf16_hi(float f) {
    __hip_bfloat16 h = __float2bfloat16(f);
    return *reinterpret_cast<short*>(&h);
}
__device__ __forceinline__ float bf16_val(short s) {
    __hip_bfloat16 h = *reinterpret_cast<__hip_bfloat16*>(&s);
    return __bfloat162float(h);
}

// Butterfly sums via permlane swaps (r6-verified: absmax identical to shfl).
__device__ __forceinline__ float red_xor32(float v) {
    float d = v, s = v;
    asm volatile("v_permlane32_swap_b32 %0, %1" : "+v"(d), "+v"(s));
    return d + s;
}
__device__ __forceinline__ float red_xor16(float v) {
    float d = v, s = v;
    asm volatile("v_permlane16_swap_b32 %0, %1" : "+v"(d), "+v"(s));
    return d + s;
}

// ---------------- Phase 1: sequential recurrence, fp32 VALU ----------------
// r6-verified skeleton: 128 WGs x 512 thr, 2 barriers/step, r6 GEMV mappings.
// NEW: weights PINNED in VGPRs (asm anti-remat) + operand preload batches.
// GEMV1: f1 = wave*32+(lane&31), K-half kh=lane>>5, k = kh*4 + jj*8 + e
// GEMV2: f2 = wave*16+(lane&15), K-quarter kq=lane>>4, k = kq*4 + jj*16 + e
__global__ __launch_bounds__(512, 2) void rnn_phase1(
    const float* __restrict__ x,
    const float* __restrict__ hW1, const float* __restrict__ hb1,
    const float* __restrict__ hW2, const float* __restrict__ hb2,
    __hip_bfloat16* __restrict__ HallB,  // [T_*B_, H_] bf16
    float* __restrict__ outF)            // d_out; hfinal tail fp32
{
    const int b    = blockIdx.x;
    const int tid  = threadIdx.x;
    const int wave = tid >> 6, lane = tid & 63;

    __shared__ float hx[192];        // [0..127]=h fp32, [128..191]=x_t
    __shared__ float sl[256];

    const int f1 = wave * 32 + (lane & 31), kh = lane >> 5;
    const int f2 = wave * 16 + (lane & 15), kq = lane >> 4;

    // ---- stage weights into registers (k-interleaved, r6 layout) ----
    float W1r[96];
#pragma unroll
    for (int jj = 0; jj < 24; ++jj)
        *(float4*)&W1r[jj * 4] = *(const float4*)&hW1[f1 * 192 + kh * 4 + jj * 8];
    float W2r[64];
#pragma unroll
    for (int jj = 0; jj < 16; ++jj)
        *(float4*)&W2r[jj * 4] = *(const float4*)&hW2[f2 * 256 + kq * 4 + jj * 16];

    // PIN: make each weight value opaque so the loads cannot be rematerialized
    // inside the t-loop (r2-r8 confound: VGPR_Count ~100 proved weights were
    // re-loaded from L1/L2 every step).
#pragma unroll
    for (int j = 0; j < 96; ++j) asm volatile("" : "+v"(W1r[j]));
#pragma unroll
    for (int j = 0; j < 64; ++j) asm volatile("" : "+v"(W2r[j]));

    const float b1v = hb1[f1];
    const float b2v = hb2[f2];

    if (tid < 128) hx[tid] = 0.f;
    float xreg = 0.f;
    if (tid >= 448) {
        const int l = tid - 448;
        const long xb = (long)b * (T_ * DIN);
        hx[128 + l] = x[xb + l];        // x_0
        xreg        = x[xb + DIN + l];  // x_1
    }
    __syncthreads();

    for (int t = 0; t < T_; ++t) {
        // ---- Phase A: GEMV1 (preload 2x12 float4) + reduce + silu -> sl
        {
            const float* hp = &hx[kh * 4];
            float a0 = 0.f, a1 = 0.f, a2 = 0.f, a3 = 0.f;
            float4 h4[12];
#pragma unroll
            for (int jj = 0; jj < 12; ++jj) h4[jj] = *(const float4*)(hp + jj * 8);
#pragma unroll
            for (int jj = 0; jj < 12; jj += 2) {
                a0 += h4[jj].x * W1r[jj*4+0] + h4[jj].y * W1r[jj*4+1];
                a1 += h4[jj].z * W1r[jj*4+2] + h4[jj].w * W1r[jj*4+3];
                a2 += h4[jj+1].x * W1r[jj*4+4] + h4[jj+1].y * W1r[jj*4+5];
                a3 += h4[jj+1].z * W1r[jj*4+6] + h4[jj+1].w * W1r[jj*4+7];
            }
#pragma unroll
            for (int jj = 0; jj < 12; ++jj) h4[jj] = *(const float4*)(hp + (jj + 12) * 8);
#pragma unroll
            for (int jj = 0; jj < 12; jj += 2) {
                a0 += h4[jj].x * W1r[48+jj*4+0] + h4[jj].y * W1r[48+jj*4+1];
                a1 += h4[jj].z * W1r[48+jj*4+2] + h4[jj].w * W1r[48+jj*4+3];
                a2 += h4[jj+1].x * W1r[48+jj*4+4] + h4[jj+1].y * W1r[48+jj*4+5];
                a3 += h4[jj+1].z * W1r[48+jj*4+6] + h4[jj+1].w * W1r[48+jj*4+7];
            }
            float v = red_xor32((a0 + a1) + (a2 + a3));
            v += b1v;
            const float s = v / (1.f + expf(-v));
            if (lane < 32) sl[f1] = s;
        }
        bar_lds();

        // ---- Phase B: GEMV2 (preload 2x8 float4) + reduces -> h_new; x install
        {
            const float* sp = &sl[kq * 4];
            float c0 = 0.f, c1 = 0.f, c2 = 0.f, c3 = 0.f;
            float4 s4[8];
#pragma unroll
            for (int jj = 0; jj < 8; ++jj) s4[jj] = *(const float4*)(sp + jj * 16);
#pragma unroll
            for (int jj = 0; jj < 8; jj += 2) {
                c0 += s4[jj].x * W2r[jj*4+0] + s4[jj].y * W2r[jj*4+1];
                c1 += s4[jj].z * W2r[jj*4+2] + s4[jj].w * W2r[jj*4+3];
                c2 += s4[jj+1].x * W2r[jj*4+4] + s4[jj+1].y * W2r[jj*4+5];
                c3 += s4[jj+1].z * W2r[jj*4+6] + s4[jj+1].w * W2r[jj*4+7];
            }
#pragma unroll
            for (int jj = 0; jj < 8; ++jj) s4[jj] = *(const float4*)(sp + (jj + 8) * 16);
#pragma unroll
            for (int jj = 0; jj < 8; jj += 2) {
                c0 += s4[jj].x * W2r[32+jj*4+0] + s4[jj].y * W2r[32+jj*4+1];
                c1 += s4[jj].z * W2r[32+jj*4+2] + s4[jj].w * W2r[32+jj*4+3];
                c2 += s4[jj+1].x * W2r[32+jj*4+4] + s4[jj+1].y * W2r[32+jj*4+5];
                c3 += s4[jj+1].z * W2r[32+jj*4+6] + s4[jj+1].w * W2r[32+jj*4+7];
            }
            float hv = red_xor16((c0 + c1) + (c2 + c3));
            hv = red_xor32(hv);
            hv += b2v;
            if (lane < 16) {
                hx[f2] = hv;                  // fp32 recurrent state
                HallB[((long)t * B_ + b) * H_ + f2] = __float2bfloat16(hv);
            }
            if (tid >= 448) {                 // x_{t+1} install + prefetch
                const int l = tid - 448;
                hx[128 + l] = xreg;
                const int tn = (t + 2 < T_) ? (t + 2) : (T_ - 1);
                xreg = x[(long)b * (T_ * DIN) + (long)tn * DIN + l];
            }
        }
        bar_lds();
    }

    if (tid < 128)
        outF[(long)B_ * T_ * DOUT + (long)b * H_ + tid] = hx[tid];
}

// -------- pre-split y-weights into MFMA-frag-linear bf16 hi/lo -------------
__global__ __launch_bounds__(256) void presplit(
    const float* __restrict__ yW1, const float* __restrict__ yW2,
    short* __restrict__ Y1f, short* __restrict__ Y2f)
{
    const int i = blockIdx.x * 256 + threadIdx.x;
    if (i < 32768) {
        const int j = i & 7, lane = (i >> 3) & 63, ks = (i >> 9) & 3, nt = i >> 11;
        const float v = yW1[(nt * 16 + (lane & 15)) * 128 + (lane >> 4) * 8 + ks * 32 + j];
        const short h = bf16_hi(v);
        Y1f[i]         = h;
        Y1f[32768 + i] = bf16_hi(v - bf16_val(h));
    }
    if (i < 16384) {
        const int j = i & 7, lane = (i >> 3) & 63, ks = (i >> 9) & 7, nt2 = i >> 12;
        const float v = yW2[(nt2 * 16 + (lane & 15)) * 256 + (lane >> 4) * 8 + ks * 32 + j];
        const short h = bf16_hi(v);
        Y2f[i]         = h;
        Y2f[16384 + i] = bf16_hi(v - bf16_val(h));
    }
}

// ---------------- Phase 2: y-MLP via MFMA, hi/lo split ---------------------
// 2048 WGs x 4 waves; each wave one PAIR of 16-row tiles (32 rows).
__global__ __launch_bounds__(256) void rnn_phase2(
    const __hip_bfloat16* __restrict__ HallB,
    const float* __restrict__ yb1, const float* __restrict__ yb2,
    const short* __restrict__ Y1f, const short* __restrict__ Y2f,
    float* __restrict__ out)
{
    __shared__ short u_lds[4][2][16 * 256];   // per-wave 2 tiles x 8KB

    const int tid  = threadIdx.x;
    const int wave = tid >> 6, lane = tid & 63;
    const int l15  = lane & 15, lg = lane >> 4;
    const long pair = (long)blockIdx.x * 4 + wave;   // 0..8191
    const long r0   = pair * 32;
    const floatx4 zero4 = {0.f, 0.f, 0.f, 0.f};
    const short* Hs = (const short*)HallB;

    short8 aH[2][4];
#pragma unroll
    for (int p = 0; p < 2; ++p)
#pragma unroll
        for (int ks = 0; ks < 4; ++ks)
            aH[p][ks] = *(const short8*)(Hs + (r0 + p * 16 + l15) * 128 + lg * 8 + ks * 32);

    // ---- GEMM1 + silu -> u (bf16) in LDS, XOR-swizzled
#pragma unroll
    for (int nt = 0; nt < 16; ++nt) {
        floatx4 accA = zero4, accB = zero4;
#pragma unroll
        for (int ks = 0; ks < 4; ++ks) {
            const short8 bhi = *(const short8*)(Y1f + ((nt * 4 + ks) * 512 + lane * 8));
            const short8 blo = *(const short8*)(Y1f + 32768 + ((nt * 4 + ks) * 512 + lane * 8));
            accA = __builtin_amdgcn_mfma_f32_16x16x32_bf16(aH[0][ks], bhi, accA, 0, 0, 0);
            accA = __builtin_amdgcn_mfma_f32_16x16x32_bf16(aH[0][ks], blo, accA, 0, 0, 0);
            accB = __builtin_amdgcn_mfma_f32_16x16x32_bf16(aH[1][ks], bhi, accB, 0, 0, 0);
            accB = __builtin_amdgcn_mfma_f32_16x16x32_bf16(aH[1][ks], blo, accB, 0, 0, 0);
        }
        const int col  = nt * 16 + l15;
        const float bias = yb1[col];
#pragma unroll
        for (int r = 0; r < 4; ++r) {
            const int row = lg * 4 + r;
            int byte = row * 512 + col * 2;
            byte ^= ((row & 7) << 4);
            float v = accA[r] + bias;
            *(short*)((char*)u_lds[wave][0] + byte) = bf16_hi(v / (1.f + __expf(-v)));
            v = accB[r] + bias;
            *(short*)((char*)u_lds[wave][1] + byte) = bf16_hi(v / (1.f + __expf(-v)));
        }
    }
    asm volatile("s_waitcnt lgkmcnt(0)" ::: "memory");

    // ---- GEMM2
    floatx4 acc2A[4] = {zero4, zero4, zero4, zero4};
    floatx4 acc2B[4] = {zero4, zero4, zero4, zero4};
#pragma unroll
    for (int ks = 0; ks < 8; ++ks) {
        int byte = l15 * 512 + (lg * 8 + ks * 32) * 2;
        byte ^= ((l15 & 7) << 4);
        const short8 aUa = *(const short8*)((char*)u_lds[wave][0] + byte);
        const short8 aUb = *(const short8*)((char*)u_lds[wave][1] + byte);
#pragma unroll
        for (int nt = 0; nt < 4; ++nt) {
            const short8 bhi = *(const short8*)(Y2f + ((nt * 8 + ks) * 512 + lane * 8));
            const short8 blo = *(const short8*)(Y2f + 16384 + ((nt * 8 + ks) * 512 + lane * 8));
            acc2A[nt] = __builtin_amdgcn_mfma_f32_16x16x32_bf16(aUa, bhi, acc2A[nt], 0, 0, 0);
            acc2A[nt] = __builtin_amdgcn_mfma_f32_16x16x32_bf16(aUa, blo, acc2A[nt], 0, 0, 0);
            acc2B[nt] = __builtin_amdgcn_mfma_f32_16x16x32_bf16(aUb, bhi, acc2B[nt], 0, 0, 0);
            acc2B[nt] = __builtin_amdgcn_mfma_f32_16x16x32_bf16(aUb, blo, acc2B[nt], 0, 0, 0);
        }
    }

    // ---- epilogue: bias + fp32 store (D: col=l15+16nt, row=lg*4+r)
#pragma unroll
    for (int nt = 0; nt < 4; ++nt) {
        const int col  = nt * 16 + l15;
        const float bias = yb2[col];
#pragma unroll
        for (int r = 0; r < 4; ++r) {
            {
                const long R  = r0 + lg * 4 + r;
                const long bb = R & (B_ - 1);
                const long tt = R >> 7;
                out[bb * (T_ * DOUT) + tt * DOUT + col] = acc2A[nt][r] + bias;
            }
            {
                const long R  = r0 + 16 + lg * 4 + r;
                const long bb = R & (B_ - 1);
                const long tt = R >> 7;
                out[bb * (T_ * DOUT) + tt * DOUT + col] = acc2B[nt][r] + bias;
            }
        }
    }
}

extern "C" void kernel_launch(void* const* d_in, const int* in_sizes, int n_in,
                              void* d_out, int out_size, void* d_ws, size_t ws_size,
                              hipStream_t stream) {
    const float* x   = (const float*)d_in[0];
    const float* hW1 = (const float*)d_in[1];
    const float* hb1 = (const float*)d_in[2];
    const float* hW2 = (const float*)d_in[3];
    const float* hb2 = (const float*)d_in[4];
    const float* yW1 = (const float*)d_in[5];
    const float* yb1 = (const float*)d_in[6];
    const float* yW2 = (const float*)d_in[7];
    const float* yb2 = (const float*)d_in[8];

    float* out = (float*)d_out;
    __hip_bfloat16* HallB = (__hip_bfloat16*)d_ws;               // 64 MiB
    const size_t hallBytes = (size_t)T_ * B_ * H_ * sizeof(__hip_bfloat16);
    short* Y1f = (short*)((char*)d_ws + hallBytes);              // 128 KB (hi+lo)
    short* Y2f = Y1f + 65536;                                    // 64 KB

    rnn_phase1<<<128, 512, 0, stream>>>(x, hW1, hb1, hW2, hb2, HallB, out);
    presplit<<<128, 256, 0, stream>>>(yW1, yW2, Y1f, Y2f);
    rnn_phase2<<<2048, 256, 0, stream>>>(HallB, yb1, yb2, Y1f, Y2f, out);
}